// Round 12
// baseline (2797.487 us; speedup 1.0000x reference)
//
#include <hip/hip_runtime.h>

// GMAN pipeline, fully fused, MFMA edition — R12: BARRIER-FREE transposed dataflow.
// support = I -> per-(b,n) independence. B=64, P=Q=12, N=1024, D=64. Out [B,Q,N] fp32.
//
// R7-R11 plateau (492us): 6-7 full-drain __syncthreads per p-step (cross-wave
// rs/state exchange) => ~20K stall cycles per p-step vs ~4K of work.
// Fix: transpose every GEMM. A = W^T (pre-laid frags, prep kernels UNCHANGED by
// A/B layout symmetry), B = activations^T, D = next activations^T. Token dim
// stays on lane&15 through the whole chain -> each wave owns 16 tokens
// end-to-end; all exchanges are wave-private LDS rows ([tok][d] packed hi|lo
// bf16 dwords, stride 68 — R10-validated bank spread) ordered by same-wave
// lgkmcnt. ZERO __syncthreads in the p-loop. State in regs + private LDS.
// Elementwise (sigmoid/tanh/update) is lane-local on C-layout tiles.

#define NB 1024
#define RSTR 68   // dwords per activation row (16 rows per wave buffer)

typedef float f32x4 __attribute__((ext_vector_type(4)));
typedef __bf16 bf16x8 __attribute__((ext_vector_type(8)));
typedef int i32x4 __attribute__((ext_vector_type(4)));
typedef unsigned int u32;
typedef unsigned short u16;

#define MFMA(a, b, c) __builtin_amdgcn_mfma_f32_16x16x32_bf16(a, b, c, 0, 0, 0)

__device__ __forceinline__ float fexp(float x) {
    return __builtin_amdgcn_exp2f(x * 1.44269504088896341f);
}
__device__ __forceinline__ float fsigmoid(float x) {
    return __builtin_amdgcn_rcpf(1.0f + fexp(-x));
}
__device__ __forceinline__ float ftanh(float x) {
    return 1.0f - 2.0f * __builtin_amdgcn_rcpf(1.0f + fexp(2.0f * x));
}

// pack fp32 -> {bf16 hi | bf16 lo} in one dword (truncation split)
__device__ __forceinline__ u32 packf(float v) {
    u32 u = __builtin_bit_cast(u32, v);
    u32 hb = u & 0xFFFF0000u;
    float lo = v - __builtin_bit_cast(float, hb);
    return hb | (__builtin_bit_cast(u32, lo) >> 16);
}

__device__ __forceinline__ bf16x8 ldfrag(const u16* p) {
    i32x4 t = *(const i32x4*)p;
    return __builtin_bit_cast(bf16x8, t);
}
__device__ __forceinline__ void split8(f32x4 a0, f32x4 a1, bf16x8& hi, bf16x8& lo) {
    #pragma unroll
    for (int i = 0; i < 4; i++) {
        __bf16 h0 = (__bf16)a0[i]; hi[i] = h0;     lo[i] = (__bf16)(a0[i] - (float)h0);
        __bf16 h1 = (__bf16)a1[i]; hi[4 + i] = h1; lo[4 + i] = (__bf16)(a1[i] - (float)h1);
    }
}

// B-frag: 8 consecutive k (packed dwords) from wave-private row tok, extract hi/lo
__device__ __forceinline__ void bfrag(const u32* buf, int tok, int koff,
                                      bf16x8& hi, bf16x8& lo) {
    const u32* p = buf + tok * RSTR + koff;
    i32x4 d0 = *(const i32x4*)p;
    i32x4 d1 = *(const i32x4*)(p + 4);
    i32x4 h, L;
    h[0] = (int)__builtin_amdgcn_perm((u32)d0[1], (u32)d0[0], 0x07060302u);
    h[1] = (int)__builtin_amdgcn_perm((u32)d0[3], (u32)d0[2], 0x07060302u);
    h[2] = (int)__builtin_amdgcn_perm((u32)d1[1], (u32)d1[0], 0x07060302u);
    h[3] = (int)__builtin_amdgcn_perm((u32)d1[3], (u32)d1[2], 0x07060302u);
    L[0] = (int)__builtin_amdgcn_perm((u32)d0[1], (u32)d0[0], 0x05040100u);
    L[1] = (int)__builtin_amdgcn_perm((u32)d0[3], (u32)d0[2], 0x05040100u);
    L[2] = (int)__builtin_amdgcn_perm((u32)d1[1], (u32)d1[0], 0x05040100u);
    L[3] = (int)__builtin_amdgcn_perm((u32)d1[3], (u32)d1[2], 0x05040100u);
    hi = __builtin_bit_cast(bf16x8, h);
    lo = __builtin_bit_cast(bf16x8, L);
}

// ---------------- ws layout (u16 units for frags; dword offsets double) ----------------
// 0      FR_G1 tiles [(wq*2+nt)*4+ks][half][lane][8]  (32768 u16) ; 32768 FR_G2
// 65536  FR_C1 [(wq*4+ks)][half][lane][8] (16384 u16) ; 81920 FR_C2
// 98304  FR_XE Win2 [(wq*2+ks)][half]... ; 106496 FR_HD Wo1
// (dwords) 57344 seB [nb][w][lane][16] fp32 ; 122880 teo [768][64] fp32

__device__ __forceinline__ void wsplit(float v, u16* dhi, u16* dlo) {
    __bf16 h = (__bf16)v;
    __bf16 l = (__bf16)(v - (float)h);
    *dhi = __builtin_bit_cast(u16, h);
    *dlo = __builtin_bit_cast(u16, l);
}

__global__ void prep_gates(const float* __restrict__ Wg1, const float* __restrict__ Wg2,
                           u16* __restrict__ fr) {
    int i = blockIdx.x * 256 + threadIdx.x;            // [0, 4096)
    if (i >= 4096) return;
    int layer = i >> 11, r = i & 2047;
    int w = r >> 9; r &= 511; int nt = r >> 8; r &= 255; int ks = r >> 6; int lane = r & 63;
    const float* Wg = layer ? Wg2 : Wg1;
    int n = lane & 15, q = lane >> 4;
    int col = nt ? (64 + w * 16 + n) : (w * 16 + n);
    u16* dst = fr + layer * 32768 + (((w * 2 + nt) * 4 + ks) * 2) * 512 + lane * 8;
    #pragma unroll
    for (int j = 0; j < 8; j++) {
        int k = ks * 32 + q * 8 + j;
        float v = Wg[k * 128 + col] + Wg[(k + 128) * 128 + col];
        wsplit(v, dst + j, dst + 512 + j);
    }
}

__global__ void prep_cand(const float* __restrict__ Wc1, const float* __restrict__ Wc2,
                          u16* __restrict__ fr) {
    int i = blockIdx.x * 256 + threadIdx.x;            // [0, 2048)
    if (i >= 2048) return;
    int layer = i >> 10, r = i & 1023;
    int w = r >> 8; r &= 255; int ks = r >> 6; int lane = r & 63;
    const float* Wc = layer ? Wc2 : Wc1;
    int n = lane & 15, q = lane >> 4;
    int col = w * 16 + n;
    u16* dst = fr + 65536 + layer * 16384 + ((w * 4 + ks) * 2) * 512 + lane * 8;
    #pragma unroll
    for (int j = 0; j < 8; j++) {
        int k = ks * 32 + q * 8 + j;
        float v = Wc[k * 64 + col] + Wc[(k + 128) * 64 + col];
        wsplit(v, dst + j, dst + 512 + j);
    }
}

__global__ void prep_small(const float* __restrict__ Win2, const float* __restrict__ Wo1,
                           u16* __restrict__ fr) {
    int i = blockIdx.x * 256 + threadIdx.x;            // [0, 1024)
    if (i >= 1024) return;
    int kind = i >> 9, r = i & 511;
    int w = r >> 7; r &= 127; int ks = r >> 6; int lane = r & 63;
    const float* W = kind ? Wo1 : Win2;
    int n = lane & 15, q = lane >> 4;
    int col = w * 16 + n;
    u16* dst = fr + 98304 + kind * 8192 + ((w * 2 + ks) * 2) * 512 + lane * 8;
    #pragma unroll
    for (int j = 0; j < 8; j++) {
        int k = ks * 32 + q * 8 + j;
        float v = W[k * 64 + col];
        wsplit(v, dst + j, dst + 512 + j);
    }
}

// se in per-lane T-layout order: token n = nb*64 + 16*w + tok, d = dt*16 + q*4 + r
// lane l = tok + 16q ; slot = dt*4 + r
__global__ void prep_se(const float* __restrict__ SE, const float* __restrict__ W1,
                        const float* __restrict__ b1, const float* __restrict__ W2,
                        const float* __restrict__ b2, const float* __restrict__ bin2,
                        float* __restrict__ seB) {
    __shared__ float h[64];
    int n = blockIdx.x, d = threadIdx.x;
    float acc = b1[d];
    for (int k = 0; k < 64; k++) acc = fmaf(SE[n * 64 + k], W1[k * 64 + d], acc);
    h[d] = fmaxf(acc, 0.0f);
    __syncthreads();
    float acc2 = b2[d];
    for (int k = 0; k < 64; k++) acc2 = fmaf(h[k], W2[k * 64 + d], acc2);
    int nb = n >> 6, w = (n >> 4) & 3, tok = n & 15;
    int dt = d >> 4, q = (d >> 2) & 3, r = d & 3;
    int l = tok + 16 * q;
    seB[(((nb * 4 + w) * 64) + l) * 16 + dt * 4 + r] = acc2 + bin2[d];
}

__global__ void prep_te(const int* __restrict__ TE, const float* __restrict__ W1,
                        const float* __restrict__ b1, const float* __restrict__ W2,
                        const float* __restrict__ b2, float* __restrict__ teo) {
    __shared__ float h[64];
    int bp = blockIdx.x;
    int b = bp / 12, p = bp - b * 12;
    int d = threadIdx.x;
    int dow = TE[(b * 24 + p) * 2 + 0];
    int tod = TE[(b * 24 + p) * 2 + 1];
    float v = W1[dow * 64 + d] + W1[(7 + tod) * 64 + d] + b1[d];
    h[d] = fmaxf(v, 0.0f);
    __syncthreads();
    float acc = b2[d];
    for (int k = 0; k < 64; k++) acc = fmaf(h[k], W2[k * 64 + d], acc);
    teo[bp * 64 + d] = acc;
}

// one GRU step, fully wave-private. Sbuf/Xbuf are this wave's LDS regions.
// sreg = state copy in regs (d = dt*16 + q*4 + r). No barriers anywhere.
__device__ __forceinline__ void gru_T(
    u32* Sbuf, u32* Xbuf, f32x4 (&sreg)[4],
    const bf16x8 (&BXh)[2], const bf16x8 (&BXl)[2],
    const u16* __restrict__ frG, const u16* __restrict__ frC,
    const float* __restrict__ bg, const float* __restrict__ bc,
    int l, int tok, int q) {
    f32x4 accR[4], accU[4], accC[4];
    #pragma unroll
    for (int dt = 0; dt < 4; dt++) {
        accR[dt] = *(const f32x4*)(bg + dt * 16 + q * 4);
        accU[dt] = *(const f32x4*)(bg + 64 + dt * 16 + q * 4);
        accC[dt] = *(const f32x4*)(bc + dt * 16 + q * 4);
    }
    // ks 0,1 (input K-half, cached frags): feeds R + U + C
    #pragma unroll
    for (int ks = 0; ks < 2; ks++) {
        #pragma unroll
        for (int dt = 0; dt < 4; dt++) {
            bf16x8 wh, wl;
            wh = ldfrag(frG + (((dt * 2 + 0) * 4 + ks) * 2 + 0) * 512 + l * 8);
            wl = ldfrag(frG + (((dt * 2 + 0) * 4 + ks) * 2 + 1) * 512 + l * 8);
            accR[dt] = MFMA(wh, BXh[ks], accR[dt]);
            accR[dt] = MFMA(wh, BXl[ks], accR[dt]);
            accR[dt] = MFMA(wl, BXh[ks], accR[dt]);
            wh = ldfrag(frG + (((dt * 2 + 1) * 4 + ks) * 2 + 0) * 512 + l * 8);
            wl = ldfrag(frG + (((dt * 2 + 1) * 4 + ks) * 2 + 1) * 512 + l * 8);
            accU[dt] = MFMA(wh, BXh[ks], accU[dt]);
            accU[dt] = MFMA(wh, BXl[ks], accU[dt]);
            accU[dt] = MFMA(wl, BXh[ks], accU[dt]);
            wh = ldfrag(frC + ((dt * 4 + ks) * 2 + 0) * 512 + l * 8);
            wl = ldfrag(frC + ((dt * 4 + ks) * 2 + 1) * 512 + l * 8);
            accC[dt] = MFMA(wh, BXh[ks], accC[dt]);
            accC[dt] = MFMA(wh, BXl[ks], accC[dt]);
            accC[dt] = MFMA(wl, BXh[ks], accC[dt]);
        }
    }
    // ks 2,3 (state K-half): gates only
    #pragma unroll
    for (int ks = 2; ks < 4; ks++) {
        bf16x8 bh, bl;
        bfrag(Sbuf, tok, (ks - 2) * 32 + q * 8, bh, bl);
        #pragma unroll
        for (int dt = 0; dt < 4; dt++) {
            bf16x8 wh, wl;
            wh = ldfrag(frG + (((dt * 2 + 0) * 4 + ks) * 2 + 0) * 512 + l * 8);
            wl = ldfrag(frG + (((dt * 2 + 0) * 4 + ks) * 2 + 1) * 512 + l * 8);
            accR[dt] = MFMA(wh, bh, accR[dt]);
            accR[dt] = MFMA(wh, bl, accR[dt]);
            accR[dt] = MFMA(wl, bh, accR[dt]);
            wh = ldfrag(frG + (((dt * 2 + 1) * 4 + ks) * 2 + 0) * 512 + l * 8);
            wl = ldfrag(frG + (((dt * 2 + 1) * 4 + ks) * 2 + 1) * 512 + l * 8);
            accU[dt] = MFMA(wh, bh, accU[dt]);
            accU[dt] = MFMA(wh, bl, accU[dt]);
            accU[dt] = MFMA(wl, bh, accU[dt]);
        }
    }
    // rs = sigmoid(r) * s  (lane-local; write into Xbuf rows — same-wave ordering)
    #pragma unroll
    for (int dt = 0; dt < 4; dt++) {
        i32x4 pw;
        #pragma unroll
        for (int r = 0; r < 4; r++)
            pw[r] = (int)packf(fsigmoid(accR[dt][r]) * sreg[dt][r]);
        *(i32x4*)(Xbuf + tok * RSTR + dt * 16 + q * 4) = pw;
    }
    // cand ks 2,3 (rs K-half)
    #pragma unroll
    for (int ks = 2; ks < 4; ks++) {
        bf16x8 bh, bl;
        bfrag(Xbuf, tok, (ks - 2) * 32 + q * 8, bh, bl);
        #pragma unroll
        for (int dt = 0; dt < 4; dt++) {
            bf16x8 wh, wl;
            wh = ldfrag(frC + ((dt * 4 + ks) * 2 + 0) * 512 + l * 8);
            wl = ldfrag(frC + ((dt * 4 + ks) * 2 + 1) * 512 + l * 8);
            accC[dt] = MFMA(wh, bh, accC[dt]);
            accC[dt] = MFMA(wh, bl, accC[dt]);
            accC[dt] = MFMA(wl, bh, accC[dt]);
        }
    }
    // state update (lane-local), refresh reg copy + LDS copy
    #pragma unroll
    for (int dt = 0; dt < 4; dt++) {
        i32x4 pw;
        #pragma unroll
        for (int r = 0; r < 4; r++) {
            float u = fsigmoid(accU[dt][r]);
            float c = ftanh(accC[dt][r]);
            float s = u * sreg[dt][r] + (1.0f - u) * c;
            sreg[dt][r] = s;
            pw[r] = (int)packf(s);
        }
        *(i32x4*)(Sbuf + tok * RSTR + dt * 16 + q * 4) = pw;
    }
}

__global__ __launch_bounds__(256, 2) void gman_main(
    const float* __restrict__ X, const float* __restrict__ ws,
    const float* __restrict__ Win1, const float* __restrict__ bin1,
    const float* __restrict__ bg1, const float* __restrict__ bc1,
    const float* __restrict__ bg2, const float* __restrict__ bc2,
    const float* __restrict__ bo1, const float* __restrict__ Wo2,
    const float* __restrict__ bo2, float* __restrict__ out) {
    // 4 waves x 3 buffers x 16 rows x 68 dw = 52224 B; all accesses wave-private
    __shared__ __align__(16) u32 LB[13056];

    const int tid = threadIdx.x;
    const int l = tid & 63;
    const int w = tid >> 6;
    const int uw = __builtin_amdgcn_readfirstlane(w);
    const int tok = l & 15, q = l >> 4;
    const int b = blockIdx.x >> 4;
    const int nb = blockIdx.x & 15;
    const int n0 = nb << 6;

    u32* S1buf = LB + uw * 3264;
    u32* S2buf = S1buf + 1088;
    u32* Xbuf  = S1buf + 2176;

    const u16* frU = (const u16*)ws;
    const u16* frG1 = frU;
    const u16* frG2 = frU + 32768;
    const u16* frC1 = frU + 65536;
    const u16* frC2 = frU + 81920;
    const u16* frX  = frU + 98304;
    const u16* frH  = frU + 106496;
    const float* seQ = ws + 57344 + (((nb * 4 + uw) * 64) + l) * 16;
    const float* teo = ws + 122880;

    // zero state (wave-private; no barrier needed)
    #pragma unroll
    for (int i = 0; i < 17; i++) { S1buf[i * 64 + l] = 0u; S2buf[i * 64 + l] = 0u; }
    f32x4 s1r[4], s2r[4];
    #pragma unroll
    for (int dt = 0; dt < 4; dt++) { s1r[dt] = (f32x4)0.0f; s2r[dt] = (f32x4)0.0f; }

    f32x4 se_v[4];
    #pragma unroll
    for (int dt = 0; dt < 4; dt++) se_v[dt] = *(const f32x4*)(seQ + dt * 4);

    #pragma unroll 1
    for (int p = 0; p < 12; p++) {
        const int bp = b * 12 + p;
        const float xv = X[bp * NB + n0 + 16 * uw + tok];
        // h1 B-frags (K=64 hidden dim): h1^T[j][tok] = relu(x*Win1[j]+bin1[j])
        bf16x8 Bh1h[2], Bh1l[2];
        #pragma unroll
        for (int ks = 0; ks < 2; ks++) {
            const int k0 = ks * 32 + q * 8;
            f32x4 w1a = *(const f32x4*)(Win1 + k0), w1b = *(const f32x4*)(Win1 + k0 + 4);
            f32x4 b1a = *(const f32x4*)(bin1 + k0), b1b = *(const f32x4*)(bin1 + k0 + 4);
            f32x4 h0, h1v;
            #pragma unroll
            for (int i = 0; i < 4; i++) {
                h0[i]  = fmaxf(fmaf(xv, w1a[i], b1a[i]), 0.0f);
                h1v[i] = fmaxf(fmaf(xv, w1b[i], b1b[i]), 0.0f);
            }
            split8(h0, h1v, Bh1h[ks], Bh1l[ks]);
        }
        // xe^T = Win2^T @ h1^T + se^T + te  (acc init = se+te)
        f32x4 accX[4];
        #pragma unroll
        for (int dt = 0; dt < 4; dt++) {
            f32x4 te4 = *(const f32x4*)(teo + bp * 64 + dt * 16 + q * 4);
            accX[dt] = se_v[dt] + te4;
        }
        #pragma unroll
        for (int ks = 0; ks < 2; ks++) {
            #pragma unroll
            for (int dt = 0; dt < 4; dt++) {
                bf16x8 wh = ldfrag(frX + ((dt * 2 + ks) * 2 + 0) * 512 + l * 8);
                bf16x8 wl = ldfrag(frX + ((dt * 2 + ks) * 2 + 1) * 512 + l * 8);
                accX[dt] = MFMA(wh, Bh1h[ks], accX[dt]);
                accX[dt] = MFMA(wh, Bh1l[ks], accX[dt]);
                accX[dt] = MFMA(wl, Bh1h[ks], accX[dt]);
            }
        }
        // write xe^T to Xbuf (packed), then cache its B-frags
        #pragma unroll
        for (int dt = 0; dt < 4; dt++) {
            i32x4 pw;
            #pragma unroll
            for (int r = 0; r < 4; r++) pw[r] = (int)packf(accX[dt][r]);
            *(i32x4*)(Xbuf + tok * RSTR + dt * 16 + q * 4) = pw;
        }
        bf16x8 BXh[2], BXl[2];
        #pragma unroll
        for (int ks = 0; ks < 2; ks++)
            bfrag(Xbuf, tok, ks * 32 + q * 8, BXh[ks], BXl[ks]);

        gru_T(S1buf, Xbuf, s1r, BXh, BXl, frG1, frC1, bg1, bc1, l, tok, q);

        #pragma unroll
        for (int ks = 0; ks < 2; ks++)
            bfrag(S1buf, tok, ks * 32 + q * 8, BXh[ks], BXl[ks]);

        gru_T(S2buf, Xbuf, s2r, BXh, BXl, frG2, frC2, bg2, bc2, l, tok, q);
    }

    // head: h^T = relu(Wo1^T @ s2^T + bo1) -> Xbuf rows as fp32, then y GEMV
    f32x4 accH[4];
    #pragma unroll
    for (int dt = 0; dt < 4; dt++)
        accH[dt] = *(const f32x4*)(bo1 + dt * 16 + q * 4);
    {
        bf16x8 bh[2], bl[2];
        #pragma unroll
        for (int ks = 0; ks < 2; ks++)
            bfrag(S2buf, tok, ks * 32 + q * 8, bh[ks], bl[ks]);
        #pragma unroll
        for (int ks = 0; ks < 2; ks++) {
            #pragma unroll
            for (int dt = 0; dt < 4; dt++) {
                bf16x8 wh = ldfrag(frH + ((dt * 2 + ks) * 2 + 0) * 512 + l * 8);
                bf16x8 wl = ldfrag(frH + ((dt * 2 + ks) * 2 + 1) * 512 + l * 8);
                accH[dt] = MFMA(wh, bh[ks], accH[dt]);
                accH[dt] = MFMA(wh, bl[ks], accH[dt]);
                accH[dt] = MFMA(wl, bh[ks], accH[dt]);
            }
        }
    }
    float* Hrow = (float*)Xbuf;
    #pragma unroll
    for (int dt = 0; dt < 4; dt++) {
        f32x4 hv;
        #pragma unroll
        for (int r = 0; r < 4; r++) hv[r] = fmaxf(accH[dt][r], 0.0f);
        *(f32x4*)(Hrow + tok * RSTR + dt * 16 + q * 4) = hv;
    }
    // y[tok][3q..3q+2] (lane reads its token's full h row; same-wave ordering)
    float y0 = bo2[3 * q + 0], y1 = bo2[3 * q + 1], y2 = bo2[3 * q + 2];
    const float* hr = Hrow + tok * RSTR;
    #pragma unroll
    for (int c = 0; c < 16; c++) {
        f32x4 hc = *(const f32x4*)(hr + c * 4);
        #pragma unroll
        for (int e = 0; e < 4; e++) {
            int j = c * 4 + e;
            y0 = fmaf(hc[e], Wo2[j * 12 + 3 * q + 0], y0);
            y1 = fmaf(hc[e], Wo2[j * 12 + 3 * q + 1], y1);
            y2 = fmaf(hc[e], Wo2[j * 12 + 3 * q + 2], y2);
        }
    }
    const int gn = n0 + 16 * uw + tok;
    out[(b * 12 + 3 * q + 0) * NB + gn] = y0;
    out[(b * 12 + 3 * q + 1) * NB + gn] = y1;
    out[(b * 12 + 3 * q + 2) * NB + gn] = y2;
}

extern "C" void kernel_launch(void* const* d_in, const int* in_sizes, int n_in,
                              void* d_out, int out_size, void* d_ws, size_t ws_size,
                              hipStream_t stream) {
    const float* X    = (const float*)d_in[0];
    // d_in[1]=ZC, d_in[2]=ZF unused by the reference
    const float* SE   = (const float*)d_in[3];
    const float* Wse1 = (const float*)d_in[4];
    const float* bse1 = (const float*)d_in[5];
    const float* Wse2 = (const float*)d_in[6];
    const float* bse2 = (const float*)d_in[7];
    const float* Wte1 = (const float*)d_in[8];
    const float* bte1 = (const float*)d_in[9];
    const float* Wte2 = (const float*)d_in[10];
    const float* bte2 = (const float*)d_in[11];
    const float* Win1 = (const float*)d_in[12];
    const float* bin1 = (const float*)d_in[13];
    const float* Win2 = (const float*)d_in[14];
    const float* bin2 = (const float*)d_in[15];
    const float* Wg1  = (const float*)d_in[16];
    const float* bg1  = (const float*)d_in[17];
    const float* Wc1  = (const float*)d_in[18];
    const float* bc1  = (const float*)d_in[19];
    const float* Wg2  = (const float*)d_in[20];
    const float* bg2  = (const float*)d_in[21];
    const float* Wc2  = (const float*)d_in[22];
    const float* bc2  = (const float*)d_in[23];
    const float* Wo1  = (const float*)d_in[24];
    const float* bo1  = (const float*)d_in[25];
    const float* Wo2  = (const float*)d_in[26];
    const float* bo2  = (const float*)d_in[27];
    const int*   TE   = (const int*)d_in[28];

    float* ws = (float*)d_ws;                  // 172032 floats = 688 KB
    u16* fr = (u16*)ws;
    float* seB = ws + 57344;
    float* teo = ws + 122880;
    float* out = (float*)d_out;

    prep_gates<<<16, 256, 0, stream>>>(Wg1, Wg2, fr);
    prep_cand<<<8, 256, 0, stream>>>(Wc1, Wc2, fr);
    prep_small<<<4, 256, 0, stream>>>(Win2, Wo1, fr);
    prep_se<<<1024, 64, 0, stream>>>(SE, Wse1, bse1, Wse2, bse2, bin2, seB);
    prep_te<<<768, 64, 0, stream>>>(TE, Wte1, bte1, Wte2, bte2, teo);
    gman_main<<<1024, 256, 0, stream>>>(X, ws, Win1, bin1, bg1, bc1, bg2, bc2,
                                        bo1, Wo2, bo2, out);
}